// Round 1
// baseline (4012.852 us; speedup 1.0000x reference)
//
#include <hip/hip_runtime.h>
#include <hip/hip_bf16.h>

// ---------------------------------------------------------------------------
// ImageCaptioningModel forward on MI355X (gfx950).
// R0: correctness-first full pipeline. One MFMA bf16 GEMM (128x128x32 tile,
// reg-staged dbuf LDS, chunk-XOR swizzle), batched variant for attention.
// Residual stream fp32; GEMM operands bf16; weights either pre-permuted to
// bf16 [N][K] (QKV einsum weights) or consumed fp32 [K][N] with in-register
// conversion (Wo/fc1/fc2/patch/lm).
// ---------------------------------------------------------------------------

typedef unsigned short u16;
typedef __bf16 bf16x8 __attribute__((ext_vector_type(8)));
typedef float f32x4 __attribute__((ext_vector_type(4)));
typedef u16 u16x8 __attribute__((ext_vector_type(8)));

__device__ __forceinline__ u16 f2bf(float f) {
  unsigned int x = __builtin_bit_cast(unsigned int, f);
  unsigned int r = (x + 0x7fffu + ((x >> 16) & 1u)) >> 16;  // RNE
  return (u16)r;
}

static inline int cdiv_i(int a, int b) { return (a + b - 1) / b; }

// ---------------------------------------------------------------------------
// GEMM: C[M,N] = act(A[M,K] @ B[K,N] + bias + res + pos)
// A: bf16 row-major, lda.
// B: BF32=0 -> bf16 B^T layout [N][K] (ldb = row stride of B^T)
//    BF32=1 -> fp32 [K][N] (ldb = N-ish row stride), converted in-register.
// Batched via blockIdx.z: z -> (zb = z/bdiv, zh = z%bdiv), element offsets.
// ---------------------------------------------------------------------------
struct GemmParams {
  const u16* A; long lda;
  const void* B; long ldb;
  void* C; long ldc;
  int M, N, K;
  const float* bias;
  const float* res; long ldres;
  const float* pos;   // patch_pos [196][N], added as pos[(row%196)*N + col]
  int gelu;
  int bdiv;
  long sAb, sAh, sBb, sBh, sCb, sCh;
};

template <int BF32, int OUTBF>
__global__ __launch_bounds__(256, 2) void gemm_k(GemmParams p) {
  __shared__ __align__(16) u16 ldsA[2][4096];
  __shared__ __align__(16) u16 ldsB[2][4096];
  const int tid = threadIdx.x;
  const int lane = tid & 63;
  const int wv = tid >> 6;
  const int wr = wv >> 1, wc = wv & 1;
  const int fs = lane >> 4, fr = lane & 15;
  const int bn = blockIdx.x, bm = blockIdx.y, z = blockIdx.z;
  const int zb = z / p.bdiv, zh = z - zb * p.bdiv;

  const u16* Ab = p.A + (long)zb * p.sAb + (long)zh * p.sAh;

  // A staging: thread owns row (tid>>1), k-half (tid&1)*16 .. +15
  const int rowA = tid >> 1, khA = tid & 1;
  const int garow = min(bm * 128 + rowA, p.M - 1);
  const u16* srcA = Ab + (long)garow * p.lda + khA * 16;
  const int swA = (rowA >> 1) & 3;
  const int eA0 = rowA * 32 + (((khA * 2 + 0) ^ swA) << 3);
  const int eA1 = rowA * 32 + (((khA * 2 + 1) ^ swA) << 3);

  // B staging
  const u16* srcBb = nullptr;
  const float* srcBf = nullptr;
  int eB0 = 0, eB1 = 0;
  if (BF32) {
    const float* Bb = (const float*)p.B + (long)zb * p.sBb + (long)zh * p.sBh;
    const int colB = tid & 127, khB = tid >> 7;
    const int gcol = min(bn * 128 + colB, p.N - 1);
    srcBf = Bb + gcol + (long)(khB * 16) * p.ldb;
    const int sw = (colB >> 1) & 3;
    eB0 = colB * 32 + (((khB * 2 + 0) ^ sw) << 3);
    eB1 = colB * 32 + (((khB * 2 + 1) ^ sw) << 3);
  } else {
    const u16* Bb = (const u16*)p.B + (long)zb * p.sBb + (long)zh * p.sBh;
    const int rowB = tid >> 1, khB = tid & 1;
    const int gcol = min(bn * 128 + rowB, p.N - 1);
    srcBb = Bb + (long)gcol * p.ldb + khB * 16;
    const int sw = (rowB >> 1) & 3;
    eB0 = rowB * 32 + (((khB * 2 + 0) ^ sw) << 3);
    eB1 = rowB * 32 + (((khB * 2 + 1) ^ sw) << 3);
  }

  // fragment LDS read offsets (chunk fs, same XOR swizzle)
  int aoff[4], boff[4];
#pragma unroll
  for (int m = 0; m < 4; ++m) {
    int row = wr * 64 + m * 16 + fr;
    aoff[m] = row * 32 + ((fs ^ ((row >> 1) & 3)) << 3);
  }
#pragma unroll
  for (int n = 0; n < 4; ++n) {
    int row = wc * 64 + n * 16 + fr;
    boff[n] = row * 32 + ((fs ^ ((row >> 1) & 3)) << 3);
  }

  f32x4 acc[4][4];
  const f32x4 zero4 = {0.f, 0.f, 0.f, 0.f};
#pragma unroll
  for (int m = 0; m < 4; ++m)
#pragma unroll
    for (int n = 0; n < 4; ++n) acc[m][n] = zero4;

  const int nk = p.K >> 5;
  u16x8 ra0, ra1, rb0, rb1;
  float fb[16];

  // prologue: tile 0
  ra0 = *(const u16x8*)(srcA);
  ra1 = *(const u16x8*)(srcA + 8);
  if (BF32) {
#pragma unroll
    for (int j = 0; j < 16; ++j) fb[j] = srcBf[(long)j * p.ldb];
  } else {
    rb0 = *(const u16x8*)(srcBb);
    rb1 = *(const u16x8*)(srcBb + 8);
  }
  *(u16x8*)&ldsA[0][eA0] = ra0;
  *(u16x8*)&ldsA[0][eA1] = ra1;
  if (BF32) {
    u16x8 w0, w1;
#pragma unroll
    for (int j = 0; j < 8; ++j) { w0[j] = f2bf(fb[j]); w1[j] = f2bf(fb[j + 8]); }
    *(u16x8*)&ldsB[0][eB0] = w0;
    *(u16x8*)&ldsB[0][eB1] = w1;
  } else {
    *(u16x8*)&ldsB[0][eB0] = rb0;
    *(u16x8*)&ldsB[0][eB1] = rb1;
  }
  __syncthreads();

  int cur = 0;
  for (int kt = 0; kt < nk; ++kt) {
    const bool more = (kt + 1) < nk;
    if (more) {
      const int ko = (kt + 1) * 32;
      ra0 = *(const u16x8*)(srcA + ko);
      ra1 = *(const u16x8*)(srcA + ko + 8);
      if (BF32) {
#pragma unroll
        for (int j = 0; j < 16; ++j) fb[j] = srcBf[(long)(ko + j) * p.ldb];
      } else {
        rb0 = *(const u16x8*)(srcBb + ko);
        rb1 = *(const u16x8*)(srcBb + ko + 8);
      }
    }
    bf16x8 af[4], bv[4];
#pragma unroll
    for (int m = 0; m < 4; ++m) af[m] = *(const bf16x8*)&ldsA[cur][aoff[m]];
#pragma unroll
    for (int n = 0; n < 4; ++n) bv[n] = *(const bf16x8*)&ldsB[cur][boff[n]];
#pragma unroll
    for (int m = 0; m < 4; ++m)
#pragma unroll
      for (int n = 0; n < 4; ++n)
        acc[m][n] = __builtin_amdgcn_mfma_f32_16x16x32_bf16(af[m], bv[n], acc[m][n], 0, 0, 0);
    if (more) {
      const int nb = cur ^ 1;
      *(u16x8*)&ldsA[nb][eA0] = ra0;
      *(u16x8*)&ldsA[nb][eA1] = ra1;
      if (BF32) {
        u16x8 w0, w1;
#pragma unroll
        for (int j = 0; j < 8; ++j) { w0[j] = f2bf(fb[j]); w1[j] = f2bf(fb[j + 8]); }
        *(u16x8*)&ldsB[nb][eB0] = w0;
        *(u16x8*)&ldsB[nb][eB1] = w1;
      } else {
        *(u16x8*)&ldsB[nb][eB0] = rb0;
        *(u16x8*)&ldsB[nb][eB1] = rb1;
      }
    }
    __syncthreads();
    cur ^= 1;
  }

  // epilogue: D row = (lane>>4)*4 + q, col = lane&15 (m89/m91-verified layout)
  const long coff = (long)zb * p.sCb + (long)zh * p.sCh;
#pragma unroll
  for (int m = 0; m < 4; ++m) {
    const int rowb = bm * 128 + wr * 64 + m * 16 + fs * 4;
#pragma unroll
    for (int n = 0; n < 4; ++n) {
      const int col = bn * 128 + wc * 64 + n * 16 + fr;
      if (col >= p.N) continue;
      const float bvv = p.bias ? p.bias[col] : 0.0f;
      const f32x4 d = acc[m][n];
#pragma unroll
      for (int q = 0; q < 4; ++q) {
        const int row = rowb + q;
        if (row >= p.M) continue;
        float v = d[q] + bvv;
        if (p.res) v += p.res[(long)row * p.ldres + col];
        if (p.pos) v += p.pos[(long)(row % 196) * p.N + col];
        if (p.gelu) v = 0.5f * v * (1.0f + erff(v * 0.70710678118654752f));
        if (OUTBF)
          ((u16*)p.C)[coff + (long)row * p.ldc + col] = f2bf(v);
        else
          ((float*)p.C)[coff + (long)row * p.ldc + col] = v;
      }
    }
  }
}

// ---------------------------------------------------------------------------
// Small kernels
// ---------------------------------------------------------------------------
__global__ void patchify_k(const float* __restrict__ img, u16* __restrict__ xp) {
  int idx = blockIdx.x * 256 + threadIdx.x;
  if (idx >= 3136 * 768) return;
  int col = idx % 768, rowt = idx / 768;
  int b = rowt / 196, pi = rowt % 196;
  int gy = pi / 14, gx = pi % 14;
  int c = col >> 8, py = (col >> 4) & 15, px = col & 15;
  float v = img[(((long)b * 3 + c) * 224 + (gy * 16 + py)) * 224 + gx * 16 + px];
  xp[idx] = f2bf(v);
}

__global__ void embed_k(const int* __restrict__ tok, const float* __restrict__ tokE,
                        const float* __restrict__ posE, float* __restrict__ y) {
  int idx = blockIdx.x * 256 + threadIdx.x;
  if (idx >= 1024 * 768) return;
  int col = idx % 768;
  int bt = idx / 768;
  int t = bt & 63;
  int tk = tok[bt];
  y[idx] = tokE[(long)tk * 768 + col] + posE[t * 768 + col];
}

__global__ __launch_bounds__(64) void ln_k(const float* __restrict__ x, const float* __restrict__ w,
                                           const float* __restrict__ b, u16* __restrict__ out, int M) {
  int row = blockIdx.x;
  if (row >= M) return;
  int lane = threadIdx.x;
  const float* xr = x + (long)row * 768;
  float v[12];
  float s = 0.f;
#pragma unroll
  for (int i = 0; i < 12; ++i) { v[i] = xr[lane + i * 64]; s += v[i]; }
  for (int o = 32; o > 0; o >>= 1) s += __shfl_xor(s, o, 64);
  float mean = s * (1.f / 768.f);
  float s2 = 0.f;
#pragma unroll
  for (int i = 0; i < 12; ++i) { float d = v[i] - mean; s2 += d * d; }
  for (int o = 32; o > 0; o >>= 1) s2 += __shfl_xor(s2, o, 64);
  float inv = rsqrtf(s2 * (1.f / 768.f) + 1e-5f);
  u16* orow = out + (long)row * 768;
#pragma unroll
  for (int i = 0; i < 12; ++i) {
    int c = lane + i * 64;
    orow[c] = f2bf((v[i] - mean) * inv * w[c] + b[c]);
  }
}

// softmax over rows of S[z][Mrows][ld]; writes bf16 P (masked/pad -> 0)
__global__ __launch_bounds__(64) void softmax_k(const float* __restrict__ S, u16* __restrict__ P,
                                                int Mrows, int ncols, int ld, int causal, float scale) {
  int row = blockIdx.x, z = blockIdx.y;
  const float* sr = S + ((long)z * Mrows + row) * ld;
  u16* pr = P + ((long)z * Mrows + row) * ld;
  int lim = causal ? (row + 1) : ncols;
  int lane = threadIdx.x;
  float vals[4];
  float mx = -1e30f;
  int nit = (ld + 63) >> 6;
  for (int i = 0; i < nit; ++i) {
    int c = lane + i * 64;
    float xv = (c < lim) ? sr[c] * scale : -1e30f;
    vals[i] = xv;
    mx = fmaxf(mx, xv);
  }
  for (int o = 32; o > 0; o >>= 1) mx = fmaxf(mx, __shfl_xor(mx, o, 64));
  float sum = 0.f;
  for (int i = 0; i < nit; ++i) {
    int c = lane + i * 64;
    float e = (c < lim) ? expf(vals[i] - mx) : 0.f;
    vals[i] = e;
    sum += e;
  }
  for (int o = 32; o > 0; o >>= 1) sum += __shfl_xor(sum, o, 64);
  float inv = 1.f / sum;
  for (int i = 0; i < nit; ++i) {
    int c = lane + i * 64;
    if (c < ld) pr[c] = f2bf(vals[i] * inv);
  }
}

// VT[z][d][s] = src[(b*Ts+s)*ldsrc + off + h*64 + d], s>=Ts -> 0 (pad)
__global__ void vtrans_k(const u16* __restrict__ src, long ldsrc, int off, u16* __restrict__ VT,
                         int Ts, int SP) {
  int idx = blockIdx.x * 256 + threadIdx.x;
  int z = blockIdx.y;
  if (idx >= 64 * SP) return;
  int d = idx / SP, sc = idx % SP;
  int b = z / 12, h = z - b * 12;
  u16 v = 0;
  if (sc < Ts) v = src[((long)b * Ts + sc) * ldsrc + off + h * 64 + d];
  VT[((long)z * 64 + d) * SP + sc] = v;
}

__global__ void cast_k(const float* __restrict__ in, u16* __restrict__ out, long n) {
  long i = (long)blockIdx.x * 256 + threadIdx.x;
  if (i < n) out[i] = f2bf(in[i]);
}

// out [L][nparts*768][768] bf16: out[l][p*768 + h*64 + d][k] = Wp[l][h][k][d]
__global__ void prepqkv_k(const float* __restrict__ W0, const float* __restrict__ W1,
                          const float* __restrict__ W2, u16* __restrict__ out, int nparts) {
  long idx = (long)blockIdx.x * 256 + threadIdx.x;
  long total = (long)4 * nparts * 768 * 768;
  if (idx >= total) return;
  int k = (int)(idx % 768);
  long t = idx / 768;
  int n = (int)(t % (nparts * 768));
  int l = (int)(t / (nparts * 768));
  int part = n / 768;
  int hd = n - part * 768;
  int h = hd >> 6, d = hd & 63;
  const float* W = (part == 0) ? W0 : ((part == 1) ? W1 : W2);
  out[idx] = f2bf(W[(((long)l * 12 + h) * 768 + k) * 64 + d]);
}

// ---------------------------------------------------------------------------
// Host side
// ---------------------------------------------------------------------------
static void launch_gemm(hipStream_t st, bool bf32, bool outbf, const void* A, long lda,
                        const void* B, long ldb, void* C, long ldc, int M, int N, int K,
                        const float* bias, const float* res, long ldres, const float* pos,
                        int gelu, int batch, int bdiv, long sAb, long sAh, long sBb, long sBh,
                        long sCb, long sCh) {
  GemmParams p;
  p.A = (const u16*)A; p.lda = lda;
  p.B = B; p.ldb = ldb;
  p.C = C; p.ldc = ldc;
  p.M = M; p.N = N; p.K = K;
  p.bias = bias; p.res = res; p.ldres = ldres; p.pos = pos; p.gelu = gelu;
  p.bdiv = bdiv;
  p.sAb = sAb; p.sAh = sAh; p.sBb = sBb; p.sBh = sBh; p.sCb = sCb; p.sCh = sCh;
  dim3 g(cdiv_i(N, 128), cdiv_i(M, 128), batch);
  dim3 blk(256);
  if (bf32) {
    if (outbf) gemm_k<1, 1><<<g, blk, 0, st>>>(p);
    else       gemm_k<1, 0><<<g, blk, 0, st>>>(p);
  } else {
    if (outbf) gemm_k<0, 1><<<g, blk, 0, st>>>(p);
    else       gemm_k<0, 0><<<g, blk, 0, st>>>(p);
  }
}

extern "C" void kernel_launch(void* const* d_in, const int* in_sizes, int n_in, void* d_out,
                              int out_size, void* d_ws, size_t ws_size, hipStream_t stream) {
  const float* img      = (const float*)d_in[0];
  const int*   tok      = (const int*)d_in[1];
  const float* patch_w  = (const float*)d_in[2];
  const float* patch_b  = (const float*)d_in[3];
  const float* patch_pos= (const float*)d_in[4];
  const float* tok_emb  = (const float*)d_in[5];
  const float* pos_emb  = (const float*)d_in[6];
  const float* enc_ln1_w= (const float*)d_in[7];
  const float* enc_ln1_b= (const float*)d_in[8];
  const float* enc_Wq   = (const float*)d_in[9];
  const float* enc_Wk   = (const float*)d_in[10];
  const float* enc_Wv   = (const float*)d_in[11];
  const float* enc_Wo   = (const float*)d_in[12];
  const float* enc_bo   = (const float*)d_in[13];
  const float* enc_ln2_w= (const float*)d_in[14];
  const float* enc_ln2_b= (const float*)d_in[15];
  const float* enc_fc1_w= (const float*)d_in[16];
  const float* enc_fc1_b= (const float*)d_in[17];
  const float* enc_fc2_w= (const float*)d_in[18];
  const float* enc_fc2_b= (const float*)d_in[19];
  const float* dec_ln1_w= (const float*)d_in[20];
  const float* dec_ln1_b= (const float*)d_in[21];
  const float* dec_sWq  = (const float*)d_in[22];
  const float* dec_sWk  = (const float*)d_in[23];
  const float* dec_sWv  = (const float*)d_in[24];
  const float* dec_sWo  = (const float*)d_in[25];
  const float* dec_sbo  = (const float*)d_in[26];
  const float* dec_ln2_w= (const float*)d_in[27];
  const float* dec_ln2_b= (const float*)d_in[28];
  const float* dec_cWq  = (const float*)d_in[29];
  const float* dec_cWk  = (const float*)d_in[30];
  const float* dec_cWv  = (const float*)d_in[31];
  const float* dec_cWo  = (const float*)d_in[32];
  const float* dec_cbo  = (const float*)d_in[33];
  const float* dec_ln3_w= (const float*)d_in[34];
  const float* dec_ln3_b= (const float*)d_in[35];
  const float* dec_fc1_w= (const float*)d_in[36];
  const float* dec_fc1_b= (const float*)d_in[37];
  const float* dec_fc2_w= (const float*)d_in[38];
  const float* dec_fc2_b= (const float*)d_in[39];
  const float* lnf_w    = (const float*)d_in[40];
  const float* lnf_b    = (const float*)d_in[41];
  const float* lm_w     = (const float*)d_in[42];
  const float* lm_b     = (const float*)d_in[43];
  float* out = (float*)d_out;
  (void)in_sizes; (void)n_in; (void)out_size; (void)ws_size;

  char* wsp = (char*)d_ws;
  size_t off = 0;
  auto alloc = [&](size_t bytes) -> void* {
    void* pp = wsp + off;
    off = (off + bytes + 255) & ~(size_t)255;
    return pp;
  };
  u16* wEncQKV  = (u16*)alloc(2ll * 4 * 2304 * 768);
  u16* wDecSQKV = (u16*)alloc(2ll * 4 * 2304 * 768);
  u16* wDecCQ   = (u16*)alloc(2ll * 4 * 768 * 768);
  u16* wDecCKV  = (u16*)alloc(2ll * 4 * 1536 * 768);
  float* xEnc   = (float*)alloc(4ll * 3136 * 768);
  u16* hBf      = (u16*)alloc(2ll * 3136 * 768);
  u16* qkv      = (u16*)alloc(2ll * 3136 * 2304);
  float* S      = (float*)alloc(4ll * 192 * 196 * 224);
  u16* P        = (u16*)alloc(2ll * 192 * 196 * 224);
  u16* VT       = (u16*)alloc(2ll * 192 * 64 * 224);
  u16* attnO    = (u16*)alloc(2ll * 3136 * 768);
  u16* uB       = (u16*)alloc(2ll * 3136 * 3072);
  u16* encB     = (u16*)alloc(2ll * 3136 * 768);
  float* yDec   = (float*)alloc(4ll * 1024 * 768);
  u16* qkvS     = (u16*)alloc(2ll * 1024 * 2304);
  u16* qC       = (u16*)alloc(2ll * 1024 * 768);
  u16* kvC      = (u16*)alloc(2ll * 3136 * 1536);
  u16* xp       = (u16*)alloc(2ll * 3136 * 768);

  // ---- weight prep (QKV einsum weights -> bf16 [N][K]) ----
  {
    long tot3 = 4ll * 3 * 768 * 768;
    prepqkv_k<<<dim3((unsigned)((tot3 + 255) / 256)), 256, 0, stream>>>(enc_Wq, enc_Wk, enc_Wv, wEncQKV, 3);
    prepqkv_k<<<dim3((unsigned)((tot3 + 255) / 256)), 256, 0, stream>>>(dec_sWq, dec_sWk, dec_sWv, wDecSQKV, 3);
    long tot1 = 4ll * 1 * 768 * 768;
    prepqkv_k<<<dim3((unsigned)((tot1 + 255) / 256)), 256, 0, stream>>>(dec_cWq, dec_cWq, dec_cWq, wDecCQ, 1);
    long tot2 = 4ll * 2 * 768 * 768;
    prepqkv_k<<<dim3((unsigned)((tot2 + 255) / 256)), 256, 0, stream>>>(dec_cWk, dec_cWv, dec_cWv, wDecCKV, 2);
  }

  // ---- patch embedding ----
  patchify_k<<<dim3(cdiv_i(3136 * 768, 256)), 256, 0, stream>>>(img, xp);
  launch_gemm(stream, true, false, xp, 768, patch_w, 768, xEnc, 768, 3136, 768, 768,
              patch_b, nullptr, 0, patch_pos, 0, 1, 1, 0, 0, 0, 0, 0, 0);

  // ---- encoder ----
  for (int l = 0; l < 4; ++l) {
    ln_k<<<3136, 64, 0, stream>>>(xEnc, enc_ln1_w + l * 768, enc_ln1_b + l * 768, hBf, 3136);
    launch_gemm(stream, false, true, hBf, 768, wEncQKV + (long)l * 2304 * 768, 768, qkv, 2304,
                3136, 2304, 768, nullptr, nullptr, 0, nullptr, 0, 1, 1, 0, 0, 0, 0, 0, 0);
    // scores: S[z] = Q @ K^T
    launch_gemm(stream, false, false, qkv, 2304, qkv + 768, 2304, S, 224, 196, 196, 64,
                nullptr, nullptr, 0, nullptr, 0, 192, 12,
                196L * 2304, 64, 196L * 2304, 64, 12L * 196 * 224, 196L * 224);
    softmax_k<<<dim3(196, 192), 64, 0, stream>>>(S, P, 196, 196, 224, 0, 0.125f);
    vtrans_k<<<dim3(cdiv_i(64 * 224, 256), 192), 256, 0, stream>>>(qkv, 2304, 1536, VT, 196, 224);
    launch_gemm(stream, false, true, P, 224, VT, 224, attnO, 768, 196, 64, 224,
                nullptr, nullptr, 0, nullptr, 0, 192, 12,
                12L * 196 * 224, 196L * 224, 12L * 64 * 224, 64L * 224, 196L * 768, 64);
    launch_gemm(stream, true, false, attnO, 768, enc_Wo + (long)l * 768 * 768, 768, xEnc, 768,
                3136, 768, 768, enc_bo + l * 768, xEnc, 768, nullptr, 0, 1, 1, 0, 0, 0, 0, 0, 0);
    ln_k<<<3136, 64, 0, stream>>>(xEnc, enc_ln2_w + l * 768, enc_ln2_b + l * 768, hBf, 3136);
    launch_gemm(stream, true, true, hBf, 768, enc_fc1_w + (long)l * 768 * 3072, 3072, uB, 3072,
                3136, 3072, 768, enc_fc1_b + l * 3072, nullptr, 0, nullptr, 1, 1, 1, 0, 0, 0, 0, 0, 0);
    launch_gemm(stream, true, false, uB, 3072, enc_fc2_w + (long)l * 3072 * 768, 768, xEnc, 768,
                3136, 768, 3072, enc_fc2_b + l * 768, xEnc, 768, nullptr, 0, 1, 1, 0, 0, 0, 0, 0, 0);
  }
  cast_k<<<dim3(cdiv_i(3136 * 768, 256)), 256, 0, stream>>>(xEnc, encB, 3136L * 768);

  // ---- decoder ----
  embed_k<<<dim3(cdiv_i(1024 * 768, 256)), 256, 0, stream>>>(tok, tok_emb, pos_emb, yDec);
  for (int l = 0; l < 4; ++l) {
    // self-attention (causal)
    ln_k<<<1024, 64, 0, stream>>>(yDec, dec_ln1_w + l * 768, dec_ln1_b + l * 768, hBf, 1024);
    launch_gemm(stream, false, true, hBf, 768, wDecSQKV + (long)l * 2304 * 768, 768, qkvS, 2304,
                1024, 2304, 768, nullptr, nullptr, 0, nullptr, 0, 1, 1, 0, 0, 0, 0, 0, 0);
    launch_gemm(stream, false, false, qkvS, 2304, qkvS + 768, 2304, S, 64, 64, 64, 64,
                nullptr, nullptr, 0, nullptr, 0, 192, 12,
                64L * 2304, 64, 64L * 2304, 64, 12L * 64 * 64, 64L * 64);
    softmax_k<<<dim3(64, 192), 64, 0, stream>>>(S, P, 64, 64, 64, 1, 0.125f);
    vtrans_k<<<dim3(cdiv_i(64 * 64, 256), 192), 256, 0, stream>>>(qkvS, 2304, 1536, VT, 64, 64);
    launch_gemm(stream, false, true, P, 64, VT, 64, attnO, 768, 64, 64, 64,
                nullptr, nullptr, 0, nullptr, 0, 192, 12,
                12L * 64 * 64, 64L * 64, 12L * 64 * 64, 64L * 64, 64L * 768, 64);
    launch_gemm(stream, true, false, attnO, 768, dec_sWo + (long)l * 768 * 768, 768, yDec, 768,
                1024, 768, 768, dec_sbo + l * 768, yDec, 768, nullptr, 0, 1, 1, 0, 0, 0, 0, 0, 0);
    // cross-attention
    ln_k<<<1024, 64, 0, stream>>>(yDec, dec_ln2_w + l * 768, dec_ln2_b + l * 768, hBf, 1024);
    launch_gemm(stream, false, true, hBf, 768, wDecCQ + (long)l * 768 * 768, 768, qC, 768,
                1024, 768, 768, nullptr, nullptr, 0, nullptr, 0, 1, 1, 0, 0, 0, 0, 0, 0);
    launch_gemm(stream, false, true, encB, 768, wDecCKV + (long)l * 1536 * 768, 768, kvC, 1536,
                3136, 1536, 768, nullptr, nullptr, 0, nullptr, 0, 1, 1, 0, 0, 0, 0, 0, 0);
    launch_gemm(stream, false, false, qC, 768, kvC, 1536, S, 224, 64, 196, 64,
                nullptr, nullptr, 0, nullptr, 0, 192, 12,
                64L * 768, 64, 196L * 1536, 64, 12L * 64 * 224, 64L * 224);
    softmax_k<<<dim3(64, 192), 64, 0, stream>>>(S, P, 64, 196, 224, 0, 0.125f);
    vtrans_k<<<dim3(cdiv_i(64 * 224, 256), 192), 256, 0, stream>>>(kvC, 1536, 768, VT, 196, 224);
    launch_gemm(stream, false, true, P, 224, VT, 224, attnO, 768, 64, 64, 224,
                nullptr, nullptr, 0, nullptr, 0, 192, 12,
                12L * 64 * 224, 64L * 224, 12L * 64 * 224, 64L * 224, 64L * 768, 64);
    launch_gemm(stream, true, false, attnO, 768, dec_cWo + (long)l * 768 * 768, 768, yDec, 768,
                1024, 768, 768, dec_cbo + l * 768, yDec, 768, nullptr, 0, 1, 1, 0, 0, 0, 0, 0, 0);
    // MLP
    ln_k<<<1024, 64, 0, stream>>>(yDec, dec_ln3_w + l * 768, dec_ln3_b + l * 768, hBf, 1024);
    launch_gemm(stream, true, true, hBf, 768, dec_fc1_w + (long)l * 768 * 3072, 3072, uB, 3072,
                1024, 3072, 768, dec_fc1_b + l * 3072, nullptr, 0, nullptr, 1, 1, 1, 0, 0, 0, 0, 0, 0);
    launch_gemm(stream, true, false, uB, 3072, dec_fc2_w + (long)l * 3072 * 768, 768, yDec, 768,
                1024, 768, 3072, dec_fc2_b + l * 768, yDec, 768, nullptr, 0, 1, 1, 0, 0, 0, 0, 0, 0);
  }

  // ---- head ----
  ln_k<<<1024, 64, 0, stream>>>(yDec, lnf_w, lnf_b, hBf, 1024);
  launch_gemm(stream, true, false, hBf, 768, lm_w, 32000, out, 32000, 1024, 32000, 768,
              lm_b, nullptr, 0, nullptr, 0, 1, 1, 0, 0, 0, 0, 0, 0);
}